// Round 13
// baseline (641.551 us; speedup 1.0000x reference)
//
#include <hip/hip_runtime.h>
#include <math.h>

// clDice topology loss, round 17: dilate img capture fused into vm pass.
// R16 lesson: bank-conflict counter is ~structural per b128 op (~6.5 cyc)
// -- uniformizing erode's pattern moved it only 4%. The binding resource is
// the per-CU LDS pipe; its cost ~ #LDS instructions. Only real lever: fewer
// ops. The center-row reload (4 b128/lane/phase) duplicates values already
// in registers during the vm pass -> software-pipeline: compute vm group j,
// process out-group j-2 with yg1[] = center group j-1 captured last iter.
// Same values, same phase position -> bit-identical. Dilate 22 -> 18 b128
// (block-phase 74 -> 66, -11%). Erode seg permutation (R16) kept (free).
// Everything else identical to R16/R11 (in-place buffer, absmax 0.0).

typedef unsigned int u32;
typedef _Float16 h2 __attribute__((ext_vector_type(2)));

#define STRD 52
#define BB   0x7BFF7BFFu   // +65504 x2 (erode pad)
#define NB   0xFBFFFBFFu   // -65504 x2 (dilate edge substitute)

__device__ __forceinline__ u32 ab(u32 hi, u32 lo) {
  return __builtin_amdgcn_alignbit(hi, lo, 16);
}
__device__ __forceinline__ u32 bcu(h2 x) { return __builtin_bit_cast(u32, x); }
__device__ __forceinline__ h2  bch(u32 x) { return __builtin_bit_cast(h2, x); }
__device__ __forceinline__ u32 pmin(u32 a, u32 b) {
  return bcu(__builtin_elementwise_min(bch(a), bch(b)));
}
__device__ __forceinline__ u32 pmax(u32 a, u32 b) {
  return bcu(__builtin_elementwise_max(bch(a), bch(b)));
}
__device__ __forceinline__ u32 pmin3(u32 a, u32 b, u32 c) { return pmin(pmin(a, b), c); }
__device__ __forceinline__ u32 pmax3(u32 a, u32 b, u32 c) { return pmax(pmax(a, b), c); }
// skel >= 0 always, so max(skel, relu(d)) == max(skel, d).
__device__ __forceinline__ u32 skup(u32 sk, u32 im, u32 op) {
  h2 d = bch(im) - bch(op);
  return bcu(__builtin_elementwise_max(bch(sk), d));
}
__device__ __forceinline__ float sigmoidf_(float x) {
  return 1.0f / (1.0f + __expf(-x));
}

__device__ __forceinline__ void load12(const u32* __restrict__ p,
                                       u32* __restrict__ r) {
  uint4 a = *(const uint4*)p;
  uint4 b = *(const uint4*)(p + 4);
  uint4 c = *(const uint4*)(p + 8);
  r[0]=a.x; r[1]=a.y; r[2]=a.z; r[3]=a.w;
  r[4]=b.x; r[5]=b.y; r[6]=b.z; r[7]=b.w;
  r[8]=c.x; r[9]=c.y; r[10]=c.z; r[11]=c.w;
}

__device__ __forceinline__ void store12(u32* __restrict__ q,
                                        const u32* __restrict__ r) {
  *(uint4*)(q)     = make_uint4(r[0], r[1], r[2],  r[3]);
  *(uint4*)(q + 4) = make_uint4(r[4], r[5], r[6],  r[7]);
  *(uint4*)(q + 8) = make_uint4(r[8], r[9], r[10], r[11]);
}

// Horizontal 3-wide min over a 12-dw vmin row; halos pre-fetched.
__device__ __forceinline__ void hrow12(const u32* __restrict__ v,
                                       u32 hl, u32 hr,
                                       u32* __restrict__ o) {
  u32 m0 = ab(v[0], hl);
  #pragma unroll
  for (int i = 0; i < 12; ++i) {
    u32 m1 = (i < 11) ? ab(v[i + 1], v[i]) : ab(hr, v[11]);
    o[i] = pmin3(m0, v[i], m1);
    m0 = m1;
  }
}

// Erode compute for one lane: reads halo rows as3-1, as3+3 of E^ph from E
// (center rows carried in e0..e2), leaves E^(ph+1) rows as3..as3+2 in
// e0..e2. NO stores (caller stores after the mid-phase barrier).
// FIRST: also load center rows (ph0, no carry yet).
template <bool FIRST>
__device__ __forceinline__ void erode_compute(
    const u32* __restrict__ E,
    int as3, int eoff, int pu, int pd, bool c0, bool c3,
    u32* __restrict__ e0, u32* __restrict__ e1, u32* __restrict__ e2)
{
  const u32* pr = E + (as3 - 1) * STRD + eoff;
  u32 rT[12], rB[12];
  load12(pr, rT);
  if (FIRST) {
    load12(pr + STRD,     e0);
    load12(pr + 2 * STRD, e1);
    load12(pr + 3 * STRD, e2);
  }
  load12(pr + 4 * STRD, rB);
  u32 t[12], v0[12], v1[12], v2[12];
  #pragma unroll
  for (int i = 0; i < 12; ++i) t[i]  = pmin(e0[i], e1[i]);
  #pragma unroll
  for (int i = 0; i < 12; ++i) v0[i] = pmin(rT[i], t[i]);
  #pragma unroll
  for (int i = 0; i < 12; ++i) v1[i] = pmin(t[i], e2[i]);
  #pragma unroll
  for (int i = 0; i < 12; ++i) v2[i] = pmin(e1[i], pmin(e2[i], rB[i]));
  // halos for all 3 rows issued up-front (hide bpermute latency)
  u32 hl0 = (u32)__builtin_amdgcn_ds_bpermute(pu, (int)v0[11]);
  u32 hr0 = (u32)__builtin_amdgcn_ds_bpermute(pd, (int)v0[0]);
  u32 hl1 = (u32)__builtin_amdgcn_ds_bpermute(pu, (int)v1[11]);
  u32 hr1 = (u32)__builtin_amdgcn_ds_bpermute(pd, (int)v1[0]);
  u32 hl2 = (u32)__builtin_amdgcn_ds_bpermute(pu, (int)v2[11]);
  u32 hr2 = (u32)__builtin_amdgcn_ds_bpermute(pd, (int)v2[0]);
  hl0 = c0 ? BB : hl0;  hr0 = c3 ? BB : hr0;
  hl1 = c0 ? BB : hl1;  hr1 = c3 ? BB : hr1;
  hl2 = c0 ? BB : hl2;  hr2 = c3 ? BB : hr2;
  hrow12(v0, hl0, hr0, e0);
  hrow12(v1, hl1, hr1, e1);
  hrow12(v2, hl2, hr2, e2);
}

__device__ __forceinline__ void erode_store(
    u32* __restrict__ E, int as3, int eoff,
    const u32* __restrict__ e0, const u32* __restrict__ e1,
    const u32* __restrict__ e2)
{
  u32* qw = E + as3 * STRD + eoff;
  store12(qw,            e0);
  store12(qw + STRD,     e1);
  store12(qw + 2 * STRD, e2);
}

// One dilate iteration, software-pipelined: compute vm group j; from j>=2
// process out-group g=j-2 (horiz max + skup) using yg1[] = center-row
// values of group j-1 captured the previous iteration (replaces the 4-b128
// center reload -- same LDS values, same phase position, bit-identical).
// Out-of-image rows redirected to the -BIG LDS row. Pure reads.
__device__ __forceinline__ void dilate_phase(
    const u32* __restrict__ E, const u32* __restrict__ NBR,
    int dr, int db, bool bu, bool bd, bool lfix, bool rfix,
    u32* __restrict__ img, u32* __restrict__ sk)
{
  const u32* pm = bu ? (E + (dr - 1) * STRD + db) : (NBR + db);
  const u32* pc = E + dr * STRD + db;
  const u32* pp = bd ? (E + (dr + 1) * STRD + db) : (NBR + db);
  u32 vm[21];      // indices 3..20 used
  u32 yg1[4];      // center values of read-group j-1 (img source)
  u32 m0 = 0;
  #pragma unroll
  for (int j = 0; j < 6; ++j) {
    uint4 x = *(const uint4*)(pm + 4 * j);
    uint4 y = *(const uint4*)(pc + 4 * j);
    uint4 z = *(const uint4*)(pp + 4 * j);
    const u32 xs[4] = {x.x, x.y, x.z, x.w};
    const u32 ys[4] = {y.x, y.y, y.z, y.w};
    const u32 zs[4] = {z.x, z.y, z.z, z.w};
    #pragma unroll
    for (int k = 0; k < 4; ++k) {
      const int i = 4 * j + k;
      if (i >= 3 && i <= 20) vm[i] = pmax3(xs[k], ys[k], zs[k]);
    }
    if (j == 1) {
      if (lfix) vm[3] = (vm[3] & 0x0000FFFFu) | 0xFBFF0000u;  // col 15
      m0 = ab(vm[4], vm[3]);
    }
    if (j == 5 && rfix)
      vm[20] = (vm[20] & 0xFFFF0000u) | 0x0000FBFFu;          // col 80
    if (j >= 2) {
      const int g = j - 2;           // out-group 0..3
      #pragma unroll
      for (int k = 0; k < 4; ++k) {
        const int i = 4 * g + k;
        u32 m1 = ab(vm[i + 5], vm[i + 4]);
        u32 op = pmax3(m0, vm[i + 4], m1);
        m0 = m1;
        sk[i] = skup(sk[i], img[i], op);
        img[i] = yg1[k];
      }
    }
    #pragma unroll
    for (int k = 0; k < 4; ++k) yg1[k] = ys[k];
  }
}

__global__ __launch_bounds__(256, 5) void skel_tile_kernel(
    const float* __restrict__ pred, const float* __restrict__ gt,
    float* __restrict__ sums)
{
  // Single in-place buffer: rows 0..95 data (row r at r*STRD), row 96 = -BIG.
  __shared__ __align__(16) u32 L[STRD * 97];
  u32* const E = L;
  const u32* const NBR = L + STRD * 96;

  const int tile = blockIdx.x;   // 16x16 tiles of 64x64
  const int b    = blockIdx.y;   // batch 0..31
  const int s    = blockIdx.z;   // 0: skel(sigmoid(pred)), 1: skel(gt)
  const int txI = tile & 15, tyI = tile >> 4;
  const int x0 = txI * 64 - 16, y0 = tyI * 64 - 16;
  const int t  = threadIdx.x;
  const size_t base = (size_t)b << 20;
  const float* __restrict__ src  = s ? gt   : pred;
  const float* __restrict__ osrc = s ? pred : gt;

  // ---- -BIG row init (the only scratch row read) ----
  for (int i = t; i < STRD; i += 256) L[STRD * 96 + i] = NB;

  // ---- load rows 5..90 x 12 chunks of 8 halfs; out-of-image = +BIG ----
  for (int i = t; i < 86 * 12; i += 256) {
    int ci = i % 12, row = i / 12 + 5;
    int gy = y0 + row, gx0 = x0 + ci * 8;
    uint4 hv;
    if ((unsigned)gy < 1024u && gx0 >= 0 && gx0 + 8 <= 1024) {
      const size_t g = base + (size_t)gy * 1024 + gx0;
      const float4 f0 = *(const float4*)&src[g];
      const float4 f1 = *(const float4*)&src[g + 4];
      float ff[8] = {f0.x, f0.y, f0.z, f0.w, f1.x, f1.y, f1.z, f1.w};
      u32 d[4];
      #pragma unroll
      for (int e = 0; e < 4; ++e) {
        float a = ff[2 * e], bb2 = ff[2 * e + 1];
        if (s == 0) { a = sigmoidf_(a); bb2 = sigmoidf_(bb2); }
        h2 p; p[0] = (_Float16)a; p[1] = (_Float16)bb2;
        d[e] = bcu(p);
      }
      hv = make_uint4(d[0], d[1], d[2], d[3]);
    } else {
      u32 d[4];
      #pragma unroll
      for (int e = 0; e < 4; ++e) {
        float va = 65504.0f, vb = 65504.0f;
        int gxa = gx0 + 2 * e, gxb = gxa + 1;
        if ((unsigned)gy < 1024u && (unsigned)gxa < 1024u) {
          va = src[base + (size_t)gy * 1024 + gxa];
          if (s == 0) va = sigmoidf_(va);
        }
        if ((unsigned)gy < 1024u && (unsigned)gxb < 1024u) {
          vb = src[base + (size_t)gy * 1024 + gxb];
          if (s == 0) vb = sigmoidf_(vb);
        }
        h2 p; p[0] = (_Float16)va; p[1] = (_Float16)vb;
        d[e] = bcu(p);
      }
      hv = make_uint4(d[0], d[1], d[2], d[3]);
    }
    *(uint4*)&E[row * STRD + ci * 4] = hv;
  }
  __syncthreads();

  const int lane = t & 63, wid = t >> 6;

  // erode role (waves 0-1): seg permuted so each quarter-wave holds
  // stride-2 segs -> uniform LDS bank-group load (R16).
  const int inner = (lane >> 2) & 3, qtr = lane >> 4;
  const int seg = ((t >> 6) << 4) + 2 * inner + 8 * (qtr & 1) + (qtr >> 1);
  const int ec = t & 3;
  const int as3 = 3 * seg;
  const bool c0 = (ec == 0), c3 = (ec == 3);
  const int pu = ((lane - 1) & 63) * 4;
  const int pd = ((lane + 1) & 63) * 4;
  const int eoff = 12 * ec;

  // dilate role (waves 2-3): q = wid-2, row dr = 16+lane
  const int q  = wid - 2;
  const int dr = 16 + lane;
  const int db = 4 + 16 * q;          // first dword of 24-dw read span
  const int gyD = y0 + dr;
  const bool bu = (gyD >= 1), bd = (gyD <= 1022);
  const bool lfix = (q == 0) && (txI == 0);
  const bool rfix = (q == 1) && (txI == 15);

  // Role-union register file: erode e0..e2 = st[0..35];
  // dilate img = st[0..15], skel = st[16..31].
  u32 st[36];
  u32* const e0 = st;
  u32* const e1 = st + 12;
  u32* const e2 = st + 24;
  u32* const img = st;
  u32* const sk  = st + 16;

  // ---- phase 0 ----
  const bool a0 = !(as3 + 2 < 6 || as3 > 89);
  if (wid < 2) {
    if (a0) erode_compute<true>(E, as3, eoff, pu, pd, c0, c3, e0, e1, e2);
  } else {
    #pragma unroll
    for (int i = 0; i < 16; ++i) sk[i] = 0;
    const u32* p = E + dr * STRD + db;
    #pragma unroll
    for (int i = 0; i < 4; ++i) {
      uint4 v = *(const uint4*)(p + 4 + 4 * i);
      img[4*i] = v.x; img[4*i+1] = v.y; img[4*i+2] = v.z; img[4*i+3] = v.w;
    }
  }
  __syncthreads();
  if (wid < 2 && a0) erode_store(E, as3, eoff, e0, e1, e2);
  __syncthreads();

  // ---- phases 1..10 (it==10: dilate only; E^11 never consumed) ----
  #pragma unroll 1
  for (int it = 1; it <= 10; ++it) {
    const bool act = (it < 10) && !(as3 + 2 < 6 + it || as3 > 89 - it);
    if (wid < 2) {
      if (act) erode_compute<false>(E, as3, eoff, pu, pd, c0, c3, e0, e1, e2);
    } else {
      dilate_phase(E, NBR, dr, db, bu, bd, lfix, rfix, img, sk);
    }
    __syncthreads();
    if (wid < 2 && act) erode_store(E, as3, eoff, e0, e1, e2);
    __syncthreads();
  }

  // ---- fused reduction: s0 = sum(skel*other), s1 = sum(skel) ----
  float s0 = 0.f, s1 = 0.f;
  if (wid >= 2) {
    const int gxb = x0 + 2 * db + 8;  // global col of first skel half
    const size_t g = base + (size_t)gyD * 1024 + gxb;
    #pragma unroll
    for (int v4i = 0; v4i < 8; ++v4i) {
      const float4 f = *(const float4*)&osrc[g + 4 * v4i];
      float o0 = f.x, o1 = f.y, o2 = f.z, o3 = f.w;
      if (s == 1) {
        o0 = sigmoidf_(o0); o1 = sigmoidf_(o1);
        o2 = sigmoidf_(o2); o3 = sigmoidf_(o3);
      }
      h2 qa = bch(sk[2 * v4i]);
      h2 qb = bch(sk[2 * v4i + 1]);
      float a0 = (float)qa[0], a1 = (float)qa[1];
      float a2 = (float)qb[0], a3 = (float)qb[1];
      s0 += a0 * o0 + a1 * o1 + a2 * o2 + a3 * o3;
      s1 += a0 + a1 + a2 + a3;
    }
  }
  for (int off = 32; off >= 1; off >>= 1) {
    s0 += __shfl_down(s0, off, 64);
    s1 += __shfl_down(s1, off, 64);
  }
  float* red = (float*)L;
  if (lane == 0) { red[wid * 2] = s0; red[wid * 2 + 1] = s1; }
  __syncthreads();
  if (t == 0) {
    atomicAdd(&sums[(s * 32 + b) * 2 + 0], red[4] + red[6]);
    atomicAdd(&sums[(s * 32 + b) * 2 + 1], red[5] + red[7]);
  }
}

__global__ void finalize_kernel(const float* __restrict__ sums,
                                float* __restrict__ out)
{
  const int t = threadIdx.x;  // 64 threads
  float cl = 0.f;
  if (t < 32) {
    float pn = sums[t * 2 + 0],        pd = sums[t * 2 + 1];
    float sn = sums[(32 + t) * 2 + 0], sd = sums[(32 + t) * 2 + 1];
    float tprec = pn / (pd + 1e-6f);
    float tsens = sn / (sd + 1e-6f);
    cl = 2.f * tprec * tsens / (tprec + tsens + 1e-6f);
  }
  for (int off = 32; off >= 1; off >>= 1) cl += __shfl_down(cl, off, 64);
  if (t == 0) out[0] = 1.f - cl / 32.f;
}

extern "C" void kernel_launch(void* const* d_in, const int* in_sizes, int n_in,
                              void* d_out, int out_size, void* d_ws, size_t ws_size,
                              hipStream_t stream) {
  const float* pred = (const float*)d_in[0];
  const float* gt   = (const float*)d_in[1];
  float* sums = (float*)d_ws;  // 128 floats: [tensor][batch][{prod,sum}]
  hipMemsetAsync(sums, 0, 128 * sizeof(float), stream);
  dim3 grid(256, 32, 2);
  skel_tile_kernel<<<grid, dim3(256), 0, stream>>>(pred, gt, sums);
  finalize_kernel<<<1, 64, 0, stream>>>(sums, (float*)d_out);
}